// Round 6
// baseline (411.664 us; speedup 1.0000x reference)
//
#include <hip/hip_runtime.h>
#include <stdint.h>

#define HH 512
#define WW 512
#define CIN 64
#define COUT 128
#define NB 4
#define HP 514          // padded rows: real y at y+1
#define WP 520          // padded cols: real x at x+1
#define STRIP 128       // x-sites per conv block
#define SCOLS 136       // staged cols per slab (130 needed, padded to 17 chunks)
#define NCHUNK 17       // 1024B chunks per slab
#define SLAB_B (SCOLS * CIN * 2)   // 17408 B

typedef __bf16 bf16x8 __attribute__((ext_vector_type(8)));
typedef float f32x4 __attribute__((ext_vector_type(4)));
typedef float f32x16 __attribute__((ext_vector_type(16)));
typedef const __attribute__((address_space(1))) uint32_t guint_t;
typedef __attribute__((address_space(3))) uint32_t luint_t;

__device__ __forceinline__ unsigned short f2bf(float f) {
    union { float f; uint32_t u; } v; v.f = f;
    uint32_t u = v.u;
    u += 0x7fffu + ((u >> 16) & 1u);   // RNE
    return (unsigned short)(u >> 16);
}
__device__ __forceinline__ float bf2f(uint32_t u) {
    union { uint32_t u; float f; } v; v.u = u << 16;
    return v.f;
}

__global__ void zero_kernel(float4* __restrict__ p, long n4) {
    long i = (long)blockIdx.x * 256 + threadIdx.x;
    const long stride = (long)gridDim.x * 256;
    const float4 z = make_float4(0.f, 0.f, 0.f, 0.f);
    for (; i < n4; i += stride) p[i] = z;
}

// Wt2 layout: [(k>>3)][co][k&7] bf16, k = (ky*3+kx)*64 + ci  (576 x 128)
__global__ void wt_transform(const float* __restrict__ w, unsigned short* __restrict__ wt2) {
    int tid = blockIdx.x * 256 + threadIdx.x;
    if (tid >= COUT * 576) return;
    int co = tid / 576;
    int k  = tid - co * 576;
    int off = k >> 6;
    int ci  = k & 63;
    int ky = off / 3;
    int kx = off - ky * 3;
    float val = w[((co * CIN + ci) * 3 + ky) * 3 + kx];
    wt2[(size_t)(k >> 3) * (COUT * 8) + co * 8 + (k & 7)] = f2bf(val);
}

// Scatter-add into bf16 padded dense via packed-bf16x2 CAS.
__global__ void scatter_kernel(const float* __restrict__ feat,
                               const int* __restrict__ coors,
                               uint32_t* __restrict__ dpad, int npts) {
    int t = blockIdx.x * 256 + threadIdx.x;
    int p = t >> 5;
    int c2 = t & 31;
    if (p >= npts) return;
    int b = coors[p * 3 + 0];
    int y = coors[p * 3 + 1];
    int x = coors[p * 3 + 2];
    uint32_t* wp = dpad + (((size_t)b * HP + (y + 1)) * WP + (x + 1)) * (CIN / 2) + c2;
    float ax = feat[(size_t)p * CIN + c2 * 2];
    float ay = feat[(size_t)p * CIN + c2 * 2 + 1];
    uint32_t old = *wp, assumed;
    do {
        assumed = old;
        uint32_t nv = (uint32_t)f2bf(bf2f(assumed & 0xffffu) + ax)
                    | ((uint32_t)f2bf(bf2f(assumed >> 16) + ay) << 16);
        old = atomicCAS(wp, assumed, nv);
    } while (old != assumed);
}

// One-shot conv block: (batch, 2 output rows, 128-site strip), all 128 co.
// Stage 4 input rows via global_load_lds (linear dest, inverse-swizzled src).
// 4 waves, each 64 sites x 64 co x 2 rows with mfma_32x32x16; weight
// fragments register-reused across both rows (halves weight L2 traffic).
__global__ __launch_bounds__(256, 2) void conv_kernel(
        const __bf16* __restrict__ dpad,
        const __bf16* __restrict__ wt2,
        float* __restrict__ out) {
    __shared__ __align__(16) __bf16 lds[4 * SCOLS * CIN];

    const int bid = blockIdx.x;
    const int xs = bid & 3;
    const int yb = (bid >> 2) & 255;
    const int b  = bid >> 10;
    const int x0 = xs * STRIP;
    const int y0 = yb * 2;
    const int tid = threadIdx.x;
    const int wave = tid >> 6;
    const int lane = tid & 63;
    const int lo5 = lane & 31;
    const int hi  = lane >> 5;
    const int site_base = (wave & 1) * 64;
    const int co_base   = (wave >> 1) * 64;

    // stage padded rows y0..y0+3 (= input rows y0-1..y0+2) into slabs 0..3
    const char* gbase = (const char*)dpad;
    #pragma unroll
    for (int r = 0; r < 4; ++r) {
        const char* rowp = gbase + (((size_t)b * HP + (y0 + r)) * WP + x0) * (CIN * 2);
        char* lslab = ((char*)lds) + r * SLAB_B;
        #pragma unroll
        for (int i = 0; i < 5; ++i) {
            int c = wave + i * 4;
            if (c < NCHUNK) {
                int P = c * 1024 + lane * 16;
                int L = P ^ (((P >> 7) & 7) << 4);   // involution on bits 6:4
                __builtin_amdgcn_global_load_lds(
                    (guint_t*)(rowp + L), (luint_t*)(lslab + c * 1024), 16, 0, 0);
            }
        }
    }
    __syncthreads();

    f32x16 acc[2][2][2];   // [row][mt][nt], fully static indexing
    #pragma unroll
    for (int r = 0; r < 2; ++r)
        #pragma unroll
        for (int mt = 0; mt < 2; ++mt)
            #pragma unroll
            for (int nt = 0; nt < 2; ++nt)
                acc[r][mt][nt] = (f32x16){0.f,0.f,0.f,0.f,0.f,0.f,0.f,0.f,
                                          0.f,0.f,0.f,0.f,0.f,0.f,0.f,0.f};

    #pragma unroll
    for (int off = 0; off < 9; ++off) {
        const int ky = off / 3;
        const int kx = off - ky * 3;
        #pragma unroll
        for (int ch4 = 0; ch4 < 4; ++ch4) {
            // B = weights: lane col = lo5 (co), k = hi*8+e within this K=16 step
            const __bf16* bb = wt2 + (size_t)(off * 8 + ch4 * 2 + hi) * (COUT * 8);
            bf16x8 bw[2];
            #pragma unroll
            for (int nt = 0; nt < 2; ++nt)
                bw[nt] = *reinterpret_cast<const bf16x8*>(
                    &bb[(co_base + nt * 32 + lo5) * 8]);
            // reuse bw across both output rows (register-cached weights)
            #pragma unroll
            for (int r = 0; r < 2; ++r) {
                const char* slab = (const char*)lds + (r + ky) * SLAB_B;
                bf16x8 a[2];   // A = sites: lane row = lo5, k = hi*8+e
                #pragma unroll
                for (int mt = 0; mt < 2; ++mt) {
                    int col = site_base + mt * 32 + lo5 + kx;
                    int eb = (ch4 * 32 + hi * 16) ^ ((col & 7) << 4);
                    a[mt] = *reinterpret_cast<const bf16x8*>(slab + col * 128 + eb);
                }
                #pragma unroll
                for (int nt = 0; nt < 2; ++nt)
                    #pragma unroll
                    for (int mt = 0; mt < 2; ++mt)
                        acc[r][mt][nt] = __builtin_amdgcn_mfma_f32_32x32x16_bf16(
                            a[mt], bw[nt], acc[r][mt][nt], 0, 0, 0);
            }
        }
    }

    // D (m74/m101): col = lane&31 -> co, row = (reg&3)+8*(reg>>2)+4*(lane>>5) -> site
    #pragma unroll
    for (int r = 0; r < 2; ++r) {
        const int y = y0 + r;
        #pragma unroll
        for (int nt = 0; nt < 2; ++nt) {
            const int co = co_base + nt * 32 + lo5;
            float* orow = out + ((size_t)(b * COUT + co) * HH + y) * WW
                              + x0 + site_base + hi * 4;
            #pragma unroll
            for (int mt = 0; mt < 2; ++mt) {
                #pragma unroll
                for (int q = 0; q < 4; ++q) {
                    f32x4 v = { acc[r][mt][nt][q * 4 + 0], acc[r][mt][nt][q * 4 + 1],
                                acc[r][mt][nt][q * 4 + 2], acc[r][mt][nt][q * 4 + 3] };
                    __builtin_nontemporal_store(v,
                        reinterpret_cast<f32x4*>(&orow[mt * 32 + q * 8]));
                }
            }
        }
    }
}

extern "C" void kernel_launch(void* const* d_in, const int* in_sizes, int n_in,
                              void* d_out, int out_size, void* d_ws, size_t ws_size,
                              hipStream_t stream) {
    const float* feat  = (const float*)d_in[0];
    const int*   coors = (const int*)d_in[1];
    const float* w     = (const float*)d_in[3];
    float* out = (float*)d_out;

    const size_t dpad_bytes = (size_t)NB * HP * WP * CIN * 2;   // ~137 MB
    __bf16* dpad = (__bf16*)d_ws;
    unsigned short* wt2 = (unsigned short*)((char*)d_ws + dpad_bytes);

    const int npts = in_sizes[0] / CIN; // 200000

    hipLaunchKernelGGL(zero_kernel, dim3(2048), dim3(256), 0, stream,
                       (float4*)dpad, (long)(dpad_bytes / 16));
    hipLaunchKernelGGL(wt_transform, dim3((COUT * 576 + 255) / 256), dim3(256), 0, stream,
                       w, wt2);
    hipLaunchKernelGGL(scatter_kernel, dim3((npts * 32 + 255) / 256), dim3(256), 0, stream,
                       feat, coors, (uint32_t*)dpad, npts);
    hipLaunchKernelGGL(conv_kernel, dim3(NB * 256 * (WW / STRIP)), dim3(256), 0, stream,
                       dpad, (const __bf16*)wt2, out);
}

// Round 7
// 278.267 us; speedup vs baseline: 1.4794x; 1.4794x over previous
//
#include <hip/hip_runtime.h>
#include <stdint.h>

#define HH 512
#define WW 512
#define CIN 64
#define COUT 128
#define NB 4
#define HP 514          // padded rows: real y at y+1
#define WP 520          // padded cols: real x at x+1
#define STRIP 128       // x-sites per conv block
#define SCOLS 136       // staged cols per slab (130 needed, padded to 17 chunks)
#define NCHUNK 17       // 1024B chunks per slab
#define SLAB_B (SCOLS * CIN * 2)   // 17408 B

typedef __bf16 bf16x8 __attribute__((ext_vector_type(8)));
typedef float f32x4 __attribute__((ext_vector_type(4)));
typedef const __attribute__((address_space(1))) uint32_t guint_t;
typedef __attribute__((address_space(3))) uint32_t luint_t;

__device__ __forceinline__ unsigned short f2bf(float f) {
    union { float f; uint32_t u; } v; v.f = f;
    uint32_t u = v.u;
    u += 0x7fffu + ((u >> 16) & 1u);   // RNE
    return (unsigned short)(u >> 16);
}
__device__ __forceinline__ float bf2f(uint32_t u) {
    union { uint32_t u; float f; } v; v.u = u << 16;
    return v.f;
}

// Fused init: grid-stride zero of the padded bf16 dense grid + weight
// transform to Wt2 [(k>>3)][co][k&7], k = (ky*3+kx)*64 + ci.
__global__ void init_kernel(float4* __restrict__ dz, long n4,
                            const float* __restrict__ w,
                            unsigned short* __restrict__ wt2) {
    long i = (long)blockIdx.x * 256 + threadIdx.x;
    const long stride = (long)gridDim.x * 256;
    const float4 z = make_float4(0.f, 0.f, 0.f, 0.f);
    for (long j = i; j < n4; j += stride) dz[j] = z;
    int tid = (int)i;
    if (tid < COUT * 576) {
        int co = tid / 576;
        int k  = tid - co * 576;
        int off = k >> 6;
        int ci  = k & 63;
        int ky = off / 3;
        int kx = off - ky * 3;
        float val = w[((co * CIN + ci) * 3 + ky) * 3 + kx];
        wt2[(size_t)(k >> 3) * (COUT * 8) + co * 8 + (k & 7)] = f2bf(val);
    }
}

// Scatter-add into bf16 padded dense via packed-bf16x2 CAS.
__global__ void scatter_kernel(const float* __restrict__ feat,
                               const int* __restrict__ coors,
                               uint32_t* __restrict__ dpad, int npts) {
    int t = blockIdx.x * 256 + threadIdx.x;
    int p = t >> 5;
    int c2 = t & 31;
    if (p >= npts) return;
    int b = coors[p * 3 + 0];
    int y = coors[p * 3 + 1];
    int x = coors[p * 3 + 2];
    uint32_t* wp = dpad + (((size_t)b * HP + (y + 1)) * WP + (x + 1)) * (CIN / 2) + c2;
    float ax = feat[(size_t)p * CIN + c2 * 2];
    float ay = feat[(size_t)p * CIN + c2 * 2 + 1];
    uint32_t old = *wp, assumed;
    do {
        assumed = old;
        uint32_t nv = (uint32_t)f2bf(bf2f(assumed & 0xffffu) + ax)
                    | ((uint32_t)f2bf(bf2f(assumed >> 16) + ay) << 16);
        old = atomicCAS(wp, assumed, nv);
    } while (old != assumed);
}

// One-shot conv block: (batch, 2 output rows, 128-site strip), all 128 co.
// Stage 4 input rows via global_load_lds (linear LDS dest, inverse-swizzled
// source; ds_read applies the same XOR -> conflict-free, verified R5).
// 4 waves, each 64 sites x 64 co x 2 rows, 16x16x32 MFMA. Weight fragments
// register-reused across both rows (halves weight L2 traffic, verified R6).
// acc[2][4][4] f32x4 = 128 f32 -> AGPR file.
__global__ __launch_bounds__(256, 2) void conv_kernel(
        const __bf16* __restrict__ dpad,
        const __bf16* __restrict__ wt2,
        float* __restrict__ out) {
    __shared__ __align__(16) __bf16 lds[4 * SCOLS * CIN];

    const int bid = blockIdx.x;
    const int xs = bid & 3;
    const int yb = (bid >> 2) & 255;
    const int b  = bid >> 10;
    const int x0 = xs * STRIP;
    const int y0 = yb * 2;
    const int tid = threadIdx.x;
    const int wave = tid >> 6;
    const int lane = tid & 63;
    const int lhi = lane >> 4;
    const int llo = lane & 15;
    const int site_base = (wave & 1) * 64;
    const int co_base   = (wave >> 1) * 64;

    // stage padded rows y0..y0+3 (= input rows y0-1..y0+2) into slabs 0..3
    const char* gbase = (const char*)dpad;
    #pragma unroll
    for (int r = 0; r < 4; ++r) {
        const char* rowp = gbase + (((size_t)b * HP + (y0 + r)) * WP + x0) * (CIN * 2);
        char* lslab = ((char*)lds) + r * SLAB_B;
        #pragma unroll
        for (int i = 0; i < 5; ++i) {
            int c = wave + i * 4;
            if (c < NCHUNK) {
                int P = c * 1024 + lane * 16;
                int L = P ^ (((P >> 7) & 7) << 4);   // involution on bits 6:4
                __builtin_amdgcn_global_load_lds(
                    (guint_t*)(rowp + L), (luint_t*)(lslab + c * 1024), 16, 0, 0);
            }
        }
    }
    __syncthreads();

    f32x4 acc[2][4][4];   // [row][mt][nt], static indexing -> AGPRs
    #pragma unroll
    for (int r = 0; r < 2; ++r)
        #pragma unroll
        for (int mt = 0; mt < 4; ++mt)
            #pragma unroll
            for (int nt = 0; nt < 4; ++nt)
                acc[r][mt][nt] = (f32x4){0.f, 0.f, 0.f, 0.f};

    #pragma unroll
    for (int off = 0; off < 9; ++off) {
        const int ky = off / 3;
        const int kx = off - ky * 3;
        #pragma unroll
        for (int ch = 0; ch < 2; ++ch) {
            // weights: load once, use for both rows
            const __bf16* bb = wt2 + (size_t)(off * 8 + ch * 4 + lhi) * (COUT * 8);
            bf16x8 bw[4];
            #pragma unroll
            for (int nt = 0; nt < 4; ++nt)
                bw[nt] = *reinterpret_cast<const bf16x8*>(
                    &bb[(co_base + nt * 16 + llo) * 8]);
            #pragma unroll
            for (int r = 0; r < 2; ++r) {
                const char* slab = (const char*)lds + (r + ky) * SLAB_B;
                bf16x8 a[4];
                #pragma unroll
                for (int mt = 0; mt < 4; ++mt) {
                    int col = site_base + mt * 16 + llo + kx;
                    int eb = (ch * 64 + lhi * 16) ^ ((col & 7) << 4);
                    a[mt] = *reinterpret_cast<const bf16x8*>(slab + col * 128 + eb);
                }
                #pragma unroll
                for (int nt = 0; nt < 4; ++nt)
                    #pragma unroll
                    for (int mt = 0; mt < 4; ++mt)
                        acc[r][mt][nt] = __builtin_amdgcn_mfma_f32_16x16x32_bf16(
                            a[mt], bw[nt], acc[r][mt][nt], 0, 0, 0);
            }
        }
    }

    // D mapping: col(llo)=co, row(lhi*4+q)=site -> reg quad = 4 consecutive x;
    // per store instr: 16 co-planes x 64B full lines (no write amplification).
    #pragma unroll
    for (int r = 0; r < 2; ++r) {
        const int y = y0 + r;
        #pragma unroll
        for (int nt = 0; nt < 4; ++nt) {
            int co = co_base + nt * 16 + llo;
            float* orow = out + ((size_t)(b * COUT + co) * HH + y) * WW
                              + x0 + site_base + lhi * 4;
            #pragma unroll
            for (int mt = 0; mt < 4; ++mt)
                __builtin_nontemporal_store(acc[r][mt][nt],
                    reinterpret_cast<f32x4*>(&orow[mt * 16]));
        }
    }
}

extern "C" void kernel_launch(void* const* d_in, const int* in_sizes, int n_in,
                              void* d_out, int out_size, void* d_ws, size_t ws_size,
                              hipStream_t stream) {
    const float* feat  = (const float*)d_in[0];
    const int*   coors = (const int*)d_in[1];
    const float* w     = (const float*)d_in[3];
    float* out = (float*)d_out;

    const size_t dpad_bytes = (size_t)NB * HP * WP * CIN * 2;   // ~137 MB
    __bf16* dpad = (__bf16*)d_ws;
    unsigned short* wt2 = (unsigned short*)((char*)d_ws + dpad_bytes);

    const int npts = in_sizes[0] / CIN; // 200000

    hipLaunchKernelGGL(init_kernel, dim3(2048), dim3(256), 0, stream,
                       (float4*)dpad, (long)(dpad_bytes / 16), w, wt2);
    hipLaunchKernelGGL(scatter_kernel, dim3((npts * 32 + 255) / 256), dim3(256), 0, stream,
                       feat, coors, (uint32_t*)dpad, npts);
    hipLaunchKernelGGL(conv_kernel, dim3(NB * 256 * (WW / STRIP)), dim3(256), 0, stream,
                       dpad, (const __bf16*)wt2, out);
}